// Round 1
// 1064.456 us; speedup vs baseline: 1.0006x; 1.0006x over previous
//
#include <hip/hip_runtime.h>
#include <hip/hip_fp16.h>

#define S_DIM 2048
#define D_K   64
#define BQ    64      // q rows per workgroup (16 per wave x 4 waves)
#define BK    64      // key block per iteration
#define KSTR  72      // K/P LDS row stride in halves: 64+8 pad, balanced b128 reads
#define NEGV  -1e9f
#define LOG2E 1.44269504088896f

typedef _Float16 f16;
typedef f16  f16x2 __attribute__((ext_vector_type(2)));
typedef f16  f16x4 __attribute__((ext_vector_type(4)));
typedef f16  f16x8 __attribute__((ext_vector_type(8)));
typedef float f32x4 __attribute__((ext_vector_type(4)));

// ---------------------------------------------------------------------------
// Probe: classify attn_mask storage. flag bit1 -> float32, bit0 -> byte,
// neither -> int32 {0,1}.
// ---------------------------------------------------------------------------
__global__ void mask_probe(const unsigned int* __restrict__ mw, int* __restrict__ flag) {
    int t = threadIdx.x;
    unsigned int isFloat = 0u, gt1 = 0u;
#pragma unroll
    for (int i = 0; i < 16; ++i) {
        unsigned int v = mw[t * 16 + i];
        isFloat |= (v == 0x3f800000u) ? 1u : 0u;
        gt1     |= (v > 1u) ? 1u : 0u;
    }
    if (isFloat) atomicOr(flag, 2);
    else if (gt1) atomicOr(flag, 1);
}

// ---------------------------------------------------------------------------
// Flash-style masked attention with matrix elementwise scaling.
// Softmax runs in the log2 domain (1/sqrt(dk) * log2(e) folded into Q), so
// every exponential is a single v_exp_f32. Row-sum l is computed by an extra
// ones-column MFMA (l is an O-column with V==1, identical alpha recurrence).
// Layouts (gfx950 mfma_f32_16x16x32_f16, m89/m120-verified):
//   A-frag: A[m = lane&15][k = (lane>>4)*8 + j]
//   B-frag: B[k = (lane>>4)*8 + j][n = lane&15]
//   C/D   : row = (lane>>4)*4 + reg, col = lane&15
// ---------------------------------------------------------------------------
__global__ __launch_bounds__(256, 4)
void attn_kernel(const float* __restrict__ Qg, const float* __restrict__ Kg,
                 const float* __restrict__ Vg, const void* __restrict__ maskp,
                 const float* __restrict__ Mg, float* __restrict__ Og,
                 const int* __restrict__ flagp)
{
    const int bh  = blockIdx.y;          // 0..31  (b*16+h)
    const int q0  = blockIdx.x * BQ;     // q tile origin
    const int tid = threadIdx.x;
    const int wv  = tid >> 6;            // wave 0..3
    const int ln  = tid & 63;
    const int n16 = ln & 15;
    const int qd  = ln >> 4;             // quad 0..3

    const int fl   = *flagp;
    const int mfmt = (fl & 2) ? 2 : (fl & 1);   // 0=int32 1=byte 2=float32

    const size_t bhQ = (size_t)bh * S_DIM * D_K;
    const float* Qp = Qg + bhQ;
    const float* Kp = Kg + bhQ;
    const float* Vp = Vg + bhQ;
    const size_t bhS = (size_t)bh * S_DIM * S_DIM;
    const float*         Mp = Mg + bhS;
    const unsigned char* mB = (const unsigned char*)maskp + bhS;
    const int*           mI = (const int*)maskp + bhS;
    const float*         mF = (const float*)maskp + bhS;

    __shared__ f16 Ksh[BK][KSTR];      // K block, row-major [key][dk]
    __shared__ f16 Vsh[D_K][D_K];      // V transposed [dk][key], pair-XOR swizzled
    __shared__ f16 Psh[4][16][KSTR];   // per-wave P tile [qrow][key]

    // ---- Q fragments (A layout), folded 0.125 * log2(e) (log2-domain scores) ----
    const float QSC = 0.125f * LOG2E;
    f16x8 qa[2];
    {
        const float* qp = Qp + (size_t)(q0 + wv * 16 + n16) * D_K + qd * 8;
#pragma unroll
        for (int kc = 0; kc < 2; ++kc) {
            float4 x0 = *(const float4*)(qp + kc * 32);
            float4 x1 = *(const float4*)(qp + kc * 32 + 4);
            f16x8 a;
            a[0]=(f16)(x0.x*QSC); a[1]=(f16)(x0.y*QSC);
            a[2]=(f16)(x0.z*QSC); a[3]=(f16)(x0.w*QSC);
            a[4]=(f16)(x1.x*QSC); a[5]=(f16)(x1.y*QSC);
            a[6]=(f16)(x1.z*QSC); a[7]=(f16)(x1.w*QSC);
            qa[kc] = a;
        }
    }

    f16x8 vone;
#pragma unroll
    for (int j = 0; j < 8; ++j) vone[j] = (f16)1.0f;

    float m_i[4];
    f32x4 oa[4], ol;
#pragma unroll
    for (int r = 0; r < 4; ++r) m_i[r] = -3.0e38f;
#pragma unroll
    for (int nc = 0; nc < 4; ++nc) oa[nc] = (f32x4){0.f, 0.f, 0.f, 0.f};
    ol = (f32x4){0.f, 0.f, 0.f, 0.f};

    const int qrow0 = q0 + wv * 16 + qd * 4;   // C-layout row base for this lane

    for (int kb = 0; kb < S_DIM / BK; ++kb) {
        const int k0 = kb * BK;
        __syncthreads();   // previous iteration's LDS reads complete

        // ---- stage K block -> LDS fp16 (coalesced float4 reads) ----
#pragma unroll
        for (int i = 0; i < 4; ++i) {
            int fidx = tid + i * 256;              // 0..1023
            int key  = fidx >> 4;
            int dk4  = (fidx & 15) << 2;
            float4 kv = *(const float4*)(Kp + (size_t)(k0 + key) * D_K + dk4);
            f16x4 h; h[0]=(f16)kv.x; h[1]=(f16)kv.y; h[2]=(f16)kv.z; h[3]=(f16)kv.w;
            *(f16x4*)&Ksh[key][dk4] = h;
        }
        // ---- stage V block transposed; pair-XOR swizzle spreads the f16x2
        //      writes over all 32 banks (linear layout was 8 lanes/bank) ----
#pragma unroll
        for (int i = 0; i < 2; ++i) {
            int fidx = tid + i * 256;              // 0..511
            int kp2  = fidx >> 4;                  // key pair 0..31
            int u    = fidx & 15;                  // dk/4
            const float* vp = Vp + (size_t)(k0 + kp2 * 2) * D_K + u * 4;
            float4 v0 = *(const float4*)(vp);
            float4 v1 = *(const float4*)(vp + D_K);
            float v0a[4] = {v0.x, v0.y, v0.z, v0.w};
            float v1a[4] = {v1.x, v1.y, v1.z, v1.w};
            int pp = kp2 ^ ((u & 7) << 2);         // physical pair index
#pragma unroll
            for (int c = 0; c < 4; ++c) {
                f16x2 h; h[0] = (f16)v0a[c]; h[1] = (f16)v1a[c];
                *(f16x2*)&Vsh[u * 4 + c][pp * 2] = h;
            }
        }
        __syncthreads();

        // ---- matrix + mask loads (streaming, C-layout positions) ----
        float mt[4][4];
        int mbits = 0;
        {
            const size_t base = (size_t)qrow0 * S_DIM + k0 + n16;
#pragma unroll
            for (int r = 0; r < 4; ++r)
#pragma unroll
                for (int cc = 0; cc < 4; ++cc)
                    mt[r][cc] = __builtin_nontemporal_load(Mp + base + (size_t)r * S_DIM + cc * 16);
            if (mfmt == 1) {
#pragma unroll
                for (int r = 0; r < 4; ++r)
#pragma unroll
                    for (int cc = 0; cc < 4; ++cc)
                        if (__builtin_nontemporal_load(mB + base + (size_t)r * S_DIM + cc * 16))
                            mbits |= 1 << (r * 4 + cc);
            } else if (mfmt == 0) {
#pragma unroll
                for (int r = 0; r < 4; ++r)
#pragma unroll
                    for (int cc = 0; cc < 4; ++cc)
                        if (__builtin_nontemporal_load(mI + base + (size_t)r * S_DIM + cc * 16))
                            mbits |= 1 << (r * 4 + cc);
            } else {
#pragma unroll
                for (int r = 0; r < 4; ++r)
#pragma unroll
                    for (int cc = 0; cc < 4; ++cc)
                        if (__builtin_nontemporal_load(mF + base + (size_t)r * S_DIM + cc * 16) != 0.f)
                            mbits |= 1 << (r * 4 + cc);
            }
        }

        // ---- S2 = (Q/8*log2e) K^T via MFMA (scores in log2 units) ----
        f32x4 sc[4];
#pragma unroll
        for (int cc = 0; cc < 4; ++cc) {
            f32x4 acc = (f32x4){0.f, 0.f, 0.f, 0.f};
#pragma unroll
            for (int kc = 0; kc < 2; ++kc) {
                f16x8 b = *(const f16x8*)&Ksh[cc * 16 + n16][kc * 32 + qd * 8];
                acc = __builtin_amdgcn_mfma_f32_16x16x32_f16(qa[kc], b, acc, 0, 0, 0);
            }
            sc[cc] = acc;
        }

        // ---- scale by matrix, apply mask (multiplicative: commutes w/ log2e) ----
#pragma unroll
        for (int cc = 0; cc < 4; ++cc)
#pragma unroll
            for (int r = 0; r < 4; ++r) {
                float s = sc[cc][r] * mt[r][cc];
                sc[cc][r] = ((mbits >> (r * 4 + cc)) & 1) ? NEGV : s;
            }

        // ---- row max: packed-f16 butterfly (8 swizzles instead of 16).
        //      m only needs consistency, not exactness -> f16 rounding is safe.
        float rm[4];
#pragma unroll
        for (int r = 0; r < 4; ++r) {
            rm[r] = fmaxf(fmaxf(sc[0][r], sc[1][r]), fmaxf(sc[2][r], sc[3][r]));
            rm[r] = fmaxf(rm[r], -3.0e4f);   // keep finite in f16 (all-masked row)
        }
        {
            union HU { f16x2 h; int u; };
            HU a, b, t;
            a.h[0] = (f16)rm[0]; a.h[1] = (f16)rm[1];
            b.h[0] = (f16)rm[2]; b.h[1] = (f16)rm[3];
#pragma unroll
            for (int off = 1; off < 16; off <<= 1) {
                t.u = __shfl_xor(a.u, off, 64);
                a.h = __builtin_elementwise_max(a.h, t.h);
                t.u = __shfl_xor(b.u, off, 64);
                b.h = __builtin_elementwise_max(b.h, t.h);
            }
            rm[0] = (float)a.h[0]; rm[1] = (float)a.h[1];
            rm[2] = (float)b.h[0]; rm[3] = (float)b.h[1];
        }

        // ---- deferred rescale: only touch O/l when some row's max grew ----
        int grow = (rm[0] > m_i[0]) | (rm[1] > m_i[1]) |
                   (rm[2] > m_i[2]) | (rm[3] > m_i[3]);
        if (__any(grow)) {
#pragma unroll
            for (int r = 0; r < 4; ++r) {
                float mn = fmaxf(m_i[r], rm[r]);
                float al = exp2f(m_i[r] - mn);
                m_i[r] = mn;
#pragma unroll
                for (int nc = 0; nc < 4; ++nc) oa[nc][r] *= al;
                ol[r] *= al;
            }
        }

        // ---- P = exp2(S2 - m) -> LDS (C-layout -> A-layout round trip) ----
#pragma unroll
        for (int cc = 0; cc < 4; ++cc)
#pragma unroll
            for (int r = 0; r < 4; ++r)
                Psh[wv][qd * 4 + r][cc * 16 + n16] = (f16)exp2f(sc[cc][r] - m_i[r]);

        // ---- O += P V ; l += P * ones (row-sum as a 5th MFMA column) ----
#pragma unroll
        for (int kc = 0; kc < 2; ++kc) {
            f16x8 a = *(const f16x8*)&Psh[wv][n16][kc * 32 + qd * 8];
            ol = __builtin_amdgcn_mfma_f32_16x16x32_f16(a, vone, ol, 0, 0, 0);
#pragma unroll
            for (int nc = 0; nc < 4; ++nc) {
                int sdw = (nc * 4 + (n16 >> 2)) & 7;          // (dk>>2)&7 of read row
                int pb  = (16 * kc + 4 * qd) ^ (sdw << 2);    // physical pair base
                f16x8 b = *(const f16x8*)&Vsh[nc * 16 + n16][pb * 2];
                oa[nc] = __builtin_amdgcn_mfma_f32_16x16x32_f16(a, b, oa[nc], 0, 0, 0);
            }
        }
    }

    // ---- epilogue: normalize and store ----
#pragma unroll
    for (int r = 0; r < 4; ++r) {
        float inv = 1.f / ol[r];
#pragma unroll
        for (int nc = 0; nc < 4; ++nc) {
            size_t off = ((size_t)bh * S_DIM + (qrow0 + r)) * D_K + nc * 16 + n16;
            __builtin_nontemporal_store(oa[nc][r] * inv, Og + off);
        }
    }
}

extern "C" void kernel_launch(void* const* d_in, const int* in_sizes, int n_in,
                              void* d_out, int out_size, void* d_ws, size_t ws_size,
                              hipStream_t stream) {
    const float* Q      = (const float*)d_in[0];
    const float* K      = (const float*)d_in[1];
    const float* V      = (const float*)d_in[2];
    const void*  mask   = d_in[3];
    const float* matrix = (const float*)d_in[4];
    float* out = (float*)d_out;
    int* flag = (int*)d_ws;

    hipMemsetAsync(flag, 0, sizeof(int), stream);
    mask_probe<<<1, 256, 0, stream>>>((const unsigned int*)mask, flag);

    dim3 grid(S_DIM / BQ, 2 * 16);   // 32 q-blocks x 32 (b,h)
    attn_kernel<<<grid, 256, 0, stream>>>(Q, K, V, mask, matrix, out, flag);
}